// Round 7
// baseline (480.474 us; speedup 1.0000x reference)
//
#include <hip/hip_runtime.h>

#define TS 40
#define BT 32
#define NT 256
#define MT 7      // m-tiles (16 rows) per wave ; M = 448 = 112 units * 4 gates
#define KC 4      // k-chunks of 32 ; K = 128 (100 h + 9 env + pad)
#define NTL 2     // n-tiles of 16 ; N = 32 batch per block

typedef short bf16x8 __attribute__((ext_vector_type(8)));
typedef float f32x4 __attribute__((ext_vector_type(4)));
typedef float f32x2 __attribute__((ext_vector_type(2)));

// LDS map (74240 B total -> 2 blocks/CU):
//  [0,57344)       gkT fp32 swizzled (32 rows x 1792 B)
//  [57344,65536)   H_hi bf16 (32 rows x 256 B)
//  [65536,73728)   H_lo bf16
//  [73728,74240)   part f32[4][32]
//  init aliases: W2s@0 (40000), h1s@40000 (12800), projs@52800 (12800; tail
//  overlaps H_hi -- projs is register-staged before H writes)
#define GKT_OFF   0
#define HHI_OFF   57344
#define HLO_OFF   65536
#define PART_OFF  73728
#define W2S_OFF   0
#define H1S_OFF   40000
#define PROJ_OFF  52800
#define SMEM_BYTES 74240

__device__ __forceinline__ unsigned short f2bf(float x) {
    unsigned u = __float_as_uint(x);
    unsigned r = u + 0x7fffu + ((u >> 16) & 1u);
    return (unsigned short)(r >> 16);
}
__device__ __forceinline__ float bf2f(unsigned short s) {
    return __uint_as_float(((unsigned)s) << 16);
}
__device__ __forceinline__ float sigf(float x) { return 1.0f / (1.0f + __expf(-x)); }
__device__ __forceinline__ float tanhf_(float x) { return 2.0f / (1.0f + __expf(-2.0f * x)) - 1.0f; }

// H (32 rows x 256B) : XOR-swizzle 16B chunks by (b&7)
__device__ __forceinline__ int hswz(int b, int byteoff) {
    return b * 256 + ((byteoff & ~15) ^ ((b & 7) << 4)) + (byteoff & 15);
}
// gkT (32 rows x 1792B = 112 chunks of 16B)
__device__ __forceinline__ int gswz(int b, int chunk) {
    return b * 1792 + ((chunk ^ (b & 7)) << 4);
}

__global__ void prep_kernel(const float* __restrict__ Wr, const float* __restrict__ Wk,
                            unsigned short* __restrict__ Am, unsigned short* __restrict__ Ah,
                            unsigned short* __restrict__ Al) {
    int gid = blockIdx.x * 256 + threadIdx.x;   // 448*128 = 57344
    int r = gid >> 7, k = gid & 127;
    int u = r >> 2, g = r & 3;
    float wm = 0.f, wkv = 0.f;
    if (u < 100) {
        int col = g * 100 + u;
        if (k < 100)      { wm = Wr[k * 400 + col]; wkv = Wk[k * 400 + col]; }
        else if (k < 109) { wm = Wk[k * 400 + col]; }
    }
    unsigned short hi = f2bf(wkv);
    Am[gid] = f2bf(wm);
    Ah[gid] = hi;
    Al[gid] = f2bf(wkv - bf2f(hi));
}

__global__ __launch_bounds__(NT, 2)
void fwdsim_kernel(const float* __restrict__ sampled_z,
                   const float* __restrict__ idm_s,
                   const float* __restrict__ sdv_acts,
                   const float* __restrict__ W1, const float* __restrict__ b1,
                   const float* __restrict__ W2, const float* __restrict__ b2,
                   const float* __restrict__ bl, const float* __restrict__ Wd,
                   const float* __restrict__ bd,
                   const float* __restrict__ sc_mean, const float* __restrict__ sc_var,
                   const unsigned short* __restrict__ Am,
                   const unsigned short* __restrict__ Ah,
                   const unsigned short* __restrict__ Al,
                   float* __restrict__ out) {
    __shared__ char sm[SMEM_BYTES];
    float* gkT  = (float*)(sm + GKT_OFF);
    char*  Hhi  = sm + HHI_OFF;
    char*  Hlo  = sm + HLO_OFF;
    float* part = (float*)(sm + PART_OFF);
    float* W2s  = (float*)(sm + W2S_OFF);
    float* h1s  = (float*)(sm + H1S_OFF);
    float* projs= (float*)(sm + PROJ_OFF);

    const int tid = threadIdx.x;
    const int w = tid >> 6, l = tid & 63, lb = l & 15, lg = l >> 4;
    const int blk = blockIdx.x;

    // ---------------- init: stage W2 ; h1 = relu(z@W1+b1) ----------------
    for (int i = tid; i < 2500; i += NT) ((f32x4*)W2s)[i] = ((const f32x4*)W2)[i];
    {
        const int e = tid >> 3, q = tid & 7;       // 32 elems x 8 threads
        const int eg = blk * BT + e;
        float zv[6];
        #pragma unroll
        for (int r = 0; r < 6; ++r) zv[r] = sampled_z[eg * 6 + r];
        #pragma unroll
        for (int m = 0; m < 13; ++m) {
            const int c = q * 13 + m;
            if (c < 100) {
                float a = b1[c];
                #pragma unroll
                for (int r = 0; r < 6; ++r) a += zv[r] * W1[r * 100 + c];
                h1s[e * 100 + c] = fmaxf(a, 0.f);
            }
        }
    }
    __syncthreads();

    // ---------------- proj = relu(h1 @ W2 + b2) -> projs ----------------
    {
        const int e = tid >> 3, q = tid & 7;
        for (int m = 0; m < 13; ++m) {
            const int c = q * 13 + m;
            if (c < 100) {
                float a = b2[c];
                for (int k = 0; k < 100; ++k) a += h1s[e * 100 + k] * W2s[k * 100 + c];
                projs[e * 100 + c] = fmaxf(a, 0.f);
            }
        }
    }
    __syncthreads();

    // ---------------- register-stage projs (it aliases the H region) ----------------
    float hv_init[16];
    {
        const int b = tid >> 3, p = tid & 7;
        #pragma unroll
        for (int kk = 0; kk < 16; ++kk) {
            const int k = p * 16 + kk;
            hv_init[kk] = (k < 100) ? projs[b * 100 + k] : 0.f;
        }
    }
    float c_st[MT][NTL];
    float wd_reg[MT];
    #pragma unroll
    for (int m = 0; m < MT; ++m) {
        const int u = w * 28 + m * 4 + lg;
        wd_reg[m] = (u < 100) ? Wd[u] : 0.f;
        #pragma unroll
        for (int n = 0; n < NTL; ++n) {
            const int b = n * 16 + lb;
            c_st[m][n] = (u < 100) ? projs[b * 100 + u] : 0.f;
        }
    }
    __syncthreads();   // projs fully consumed

    // ---------------- H init (h0 = proj, rows 100..127 = 0) ----------------
    {
        const int b = tid >> 3, p = tid & 7;
        #pragma unroll
        for (int kk = 0; kk < 16; ++kk) {
            const int k = p * 16 + kk;
            const float v = hv_init[kk];
            const unsigned short hi = f2bf(v);
            const unsigned short lo = f2bf(v - bf2f(hi));
            const int off = hswz(b, 2 * k);
            *(unsigned short*)(Hhi + off) = hi;
            *(unsigned short*)(Hlo + off) = lo;
        }
    }
    // A-fragments (resident), scalers, env prefetch
    bf16x8 afr[MT][KC];
    #pragma unroll
    for (int m = 0; m < MT; ++m)
        #pragma unroll
        for (int kc = 0; kc < KC; ++kc) {
            const int row = w * 112 + m * 16 + lb;
            afr[m][kc] = *(const bf16x8*)(Am + row * 128 + kc * 32 + lg * 8);
        }
    float ms[7], is[7];
    #pragma unroll
    for (int r = 0; r < 7; ++r) { ms[r] = sc_mean[r]; is[r] = 1.0f / sqrtf(sc_var[r]); }
    const float bd0 = bd[0];
    const int b_env = (w & 1) * 16 + lb;
    const size_t eg_env = (size_t)(blk * BT + b_env);
    const bool env_owner = (w < 2) && (lg == 0);
    f32x4 cur0 = {0,0,0,0}, cur1 = {0,0,0,0}, cur2 = {0,0,0,0};
    f32x2 curs = {0,0};
    f32x4 nxt0 = {0,0,0,0}, nxt1 = {0,0,0,0}, nxt2 = {0,0,0,0};
    f32x2 nxts = {0,0};
    if (env_owner) {
        const float* ip = idm_s + (eg_env * TS + 0) * 12;
        cur0 = *(const f32x4*)ip; cur1 = *(const f32x4*)(ip + 4); cur2 = *(const f32x4*)(ip + 8);
        curs = *(const f32x2*)(sdv_acts + (eg_env * TS + 0) * 2);
    }
    __syncthreads();   // H ready

    // ---------------- gk = bl + WkT @ proj  (bf16x3 MFMA, fp32 -> gkT) ----------------
    {
        f32x4 acc[MT][NTL];
        #pragma unroll
        for (int m = 0; m < MT; ++m)
            #pragma unroll
            for (int n = 0; n < NTL; ++n) acc[m][n] = (f32x4){0.f, 0.f, 0.f, 0.f};
        for (int kc = 0; kc < KC; ++kc) {
            bf16x8 bhi[NTL], blo[NTL];
            #pragma unroll
            for (int n = 0; n < NTL; ++n) {
                const int b = n * 16 + lb;
                const int off = hswz(b, kc * 64 + lg * 16);
                bhi[n] = *(const bf16x8*)(Hhi + off);
                blo[n] = *(const bf16x8*)(Hlo + off);
            }
            #pragma unroll
            for (int m = 0; m < MT; ++m) {
                const int row = w * 112 + m * 16 + lb;
                bf16x8 ah = *(const bf16x8*)(Ah + row * 128 + kc * 32 + lg * 8);
                bf16x8 al = *(const bf16x8*)(Al + row * 128 + kc * 32 + lg * 8);
                #pragma unroll
                for (int n = 0; n < NTL; ++n) {
                    acc[m][n] = __builtin_amdgcn_mfma_f32_16x16x32_bf16(ah, bhi[n], acc[m][n], 0, 0, 0);
                    acc[m][n] = __builtin_amdgcn_mfma_f32_16x16x32_bf16(ah, blo[n], acc[m][n], 0, 0, 0);
                    acc[m][n] = __builtin_amdgcn_mfma_f32_16x16x32_bf16(al, bhi[n], acc[m][n], 0, 0, 0);
                }
            }
        }
        #pragma unroll
        for (int m = 0; m < MT; ++m) {
            float blv[4];
            #pragma unroll
            for (int j = 0; j < 4; ++j) {
                const int row = w * 112 + m * 16 + lg * 4 + j;
                const int u = row >> 2, g = row & 3;
                blv[j] = (u < 100) ? bl[g * 100 + u] : 0.f;
            }
            const int chunk = w * 28 + m * 4 + lg;
            #pragma unroll
            for (int n = 0; n < NTL; ++n) {
                const int b = n * 16 + lb;
                f32x4 v = acc[m][n];
                v[0] += blv[0]; v[1] += blv[1]; v[2] += blv[2]; v[3] += blv[3];
                *(f32x4*)((char*)gkT + gswz(b, chunk)) = v;
            }
        }
    }
    __syncthreads();   // gkT ready

    // ---------------- main 40-step recurrence ----------------
    float ego_v = 0.f, ego_x = 0.f, prev_act = 0.f;
    for (int t = 0; t < TS; ++t) {
        // A) env owners: x9(t) -> H rows 100..108 ; prefetch t+1
        if (env_owner) {
            if (t == 0) { ego_v = cur0[0]; ego_x = cur0[3]; }
            else {
                ego_v += prev_act * 0.1f;
                ego_x += ego_v * 0.1f + 0.005f * prev_act;
            }
            const float f_veh_v = cur0[1], m_veh_v = cur0[2];
            const float f_glob_x = cur1[0], m_glob_x = cur1[1];
            const float ef_dv_t = cur1[2], ef_dx_t = cur1[3];
            const float em_dv_t = cur2[0], em_dx_t = cur2[1];
            const float f_ex = cur2[2], m_ex = cur2[3];
            const float ef_dx = (f_glob_x - ego_x) * f_ex + (1.f - f_ex) * ef_dx_t;
            const float em_dx = (m_glob_x - ego_x) * m_ex + (1.f - m_ex) * em_dx_t;
            const float ef_dv = (ego_v - f_veh_v) * f_ex + (1.f - f_ex) * ef_dv_t;
            const float em_dv = (ego_v - m_veh_v) * m_ex + (1.f - m_ex) * em_dv_t;
            float x9[9];
            x9[0] = curs[0]; x9[1] = curs[1];
            x9[2] = (ego_v   - ms[0]) * is[0];
            x9[3] = (f_veh_v - ms[1]) * is[1];
            x9[4] = (m_veh_v - ms[2]) * is[2];
            x9[5] = (ef_dv   - ms[3]) * is[3];
            x9[6] = (ef_dx   - ms[4]) * is[4];
            x9[7] = (em_dv   - ms[5]) * is[5];
            x9[8] = (em_dx   - ms[6]) * is[6];
            #pragma unroll
            for (int r = 0; r < 9; ++r) {
                const unsigned short hi = f2bf(x9[r]);
                const int off = hswz(b_env, 200 + 2 * r);
                *(unsigned short*)(Hhi + off) = hi;
                *(unsigned short*)(Hlo + off) = f2bf(x9[r] - bf2f(hi));
            }
            if (t < TS - 1) {
                const float* ip = idm_s + (eg_env * TS + t + 1) * 12;
                nxt0 = *(const f32x4*)ip; nxt1 = *(const f32x4*)(ip + 4); nxt2 = *(const f32x4*)(ip + 8);
                nxts = *(const f32x2*)(sdv_acts + (eg_env * TS + t + 1) * 2);
            }
        }
        __syncthreads();   // B: x9 + h visible

        // C) z^T = gk + W_combT @ [h_hi+h_lo ; x9]
        f32x4 acc[MT][NTL];
        #pragma unroll
        for (int m = 0; m < MT; ++m) {
            const int chunk = w * 28 + m * 4 + lg;
            #pragma unroll
            for (int n = 0; n < NTL; ++n)
                acc[m][n] = *(const f32x4*)((const char*)gkT + gswz(n * 16 + lb, chunk));
        }
        #pragma unroll
        for (int kc = 0; kc < KC; ++kc) {
            bf16x8 bhi[NTL], blo[NTL];
            #pragma unroll
            for (int n = 0; n < NTL; ++n) {
                const int b = n * 16 + lb;
                const int off = hswz(b, kc * 64 + lg * 16);
                bhi[n] = *(const bf16x8*)(Hhi + off);
                blo[n] = *(const bf16x8*)(Hlo + off);
            }
            #pragma unroll
            for (int m = 0; m < MT; ++m) {
                #pragma unroll
                for (int n = 0; n < NTL; ++n) {
                    acc[m][n] = __builtin_amdgcn_mfma_f32_16x16x32_bf16(afr[m][kc], bhi[n], acc[m][n], 0, 0, 0);
                    acc[m][n] = __builtin_amdgcn_mfma_f32_16x16x32_bf16(afr[m][kc], blo[n], acc[m][n], 0, 0, 0);
                }
            }
        }
        __syncthreads();   // D: all H reads done before h(t+1) writes

        // E) gates in-register; h -> LDS ; act partials
        float pact[NTL] = {0.f, 0.f};
        #pragma unroll
        for (int m = 0; m < MT; ++m) {
            const int u = w * 28 + m * 4 + lg;
            #pragma unroll
            for (int n = 0; n < NTL; ++n) {
                const int b = n * 16 + lb;
                f32x4 z = acc[m][n];
                const float cc = sigf(z[1]) * c_st[m][n] + sigf(z[0]) * tanhf_(z[2]);
                const float hh = sigf(z[3]) * tanhf_(cc);
                c_st[m][n] = cc;
                pact[n] += hh * wd_reg[m];
                if (u < 100) {
                    const unsigned short hi = f2bf(hh);
                    const int off = hswz(b, 2 * u);
                    *(unsigned short*)(Hhi + off) = hi;
                    *(unsigned short*)(Hlo + off) = f2bf(hh - bf2f(hi));
                }
            }
        }
        #pragma unroll
        for (int n = 0; n < NTL; ++n) {
            float p = pact[n];
            p += __shfl_xor(p, 16);
            p += __shfl_xor(p, 32);
            if (l < 16) part[w * 32 + n * 16 + l] = p;
        }
        __syncthreads();   // F: part + h visible

        // G) act = sum over 4 waves + bd ; output ; advance prefetch
        if (env_owner) {
            const float act = part[b_env] + part[32 + b_env] + part[64 + b_env] + part[96 + b_env] + bd0;
            out[eg_env * TS + t] = act;
            prev_act = act;
            if (t < TS - 1) { cur0 = nxt0; cur1 = nxt1; cur2 = nxt2; curs = nxts; }
        }
    }
}

extern "C" void kernel_launch(void* const* d_in, const int* in_sizes, int n_in,
                              void* d_out, int out_size, void* d_ws, size_t ws_size,
                              hipStream_t stream) {
    const float* sampled_z = (const float*)d_in[0];
    const float* idm_s     = (const float*)d_in[1];
    const float* sdv_acts  = (const float*)d_in[2];
    const float* W1        = (const float*)d_in[3];
    const float* b1        = (const float*)d_in[4];
    const float* W2        = (const float*)d_in[5];
    const float* b2        = (const float*)d_in[6];
    const float* Wk        = (const float*)d_in[7];
    const float* Wr        = (const float*)d_in[8];
    const float* bl        = (const float*)d_in[9];
    const float* Wd        = (const float*)d_in[10];
    const float* bd        = (const float*)d_in[11];
    const float* sc_mean   = (const float*)d_in[12];
    const float* sc_var    = (const float*)d_in[13];
    float* out = (float*)d_out;

    unsigned short* Am = (unsigned short*)d_ws;       // [448][128] bf16
    unsigned short* Ah = Am + 448 * 128;              // Wk-proj hi
    unsigned short* Al = Ah + 448 * 128;              // Wk-proj lo

    hipLaunchKernelGGL(prep_kernel, dim3(224), dim3(256), 0, stream, Wr, Wk, Am, Ah, Al);
    hipLaunchKernelGGL(fwdsim_kernel, dim3(16384 / BT), dim3(NT), 0, stream,
                       sampled_z, idm_s, sdv_acts, W1, b1, W2, b2, bl, Wd, bd,
                       sc_mean, sc_var, Am, Ah, Al, out);
}

// Round 8
// 419.928 us; speedup vs baseline: 1.1442x; 1.1442x over previous
//
#include <hip/hip_runtime.h>

#define TS 40
#define BT 32
#define NT 256
#define MT 7      // m-tiles (16 rows) per wave ; M = 448 = 112 units * 4 gates
#define KC 4      // k-chunks of 32 ; K = 128 (100 h + 9 env + pad)
#define NTL 2     // n-tiles of 16 ; N = 32 batch per block

typedef short bf16x8 __attribute__((ext_vector_type(8)));
typedef float f32x4 __attribute__((ext_vector_type(4)));
typedef float f32x2 __attribute__((ext_vector_type(2)));

// LDS map (74240 B total -> 2 blocks/CU):
//  [0,57344)       gkT fp32 swizzled (32 rows x 1792 B)
//  [57344,65536)   H_hi bf16 (32 rows x 256 B)
//  [65536,73728)   H_lo bf16
//  [73728,74240)   part f32[4][32]
//  init aliases: W2s@0 (40000), h1s@40000 (12800), projs@52800 (12800; tail
//  overlaps H_hi -- projs is register-staged before H writes)
#define GKT_OFF   0
#define HHI_OFF   57344
#define HLO_OFF   65536
#define PART_OFF  73728
#define W2S_OFF   0
#define H1S_OFF   40000
#define PROJ_OFF  52800
#define SMEM_BYTES 74240

__device__ __forceinline__ unsigned short f2bf(float x) {
    unsigned u = __float_as_uint(x);
    unsigned r = u + 0x7fffu + ((u >> 16) & 1u);
    return (unsigned short)(r >> 16);
}
__device__ __forceinline__ float bf2f(unsigned short s) {
    return __uint_as_float(((unsigned)s) << 16);
}
// v_rcp_f32-based (1 ulp) -- avoids the IEEE divide expansion (~10 insts each)
__device__ __forceinline__ float sigf(float x) {
    return __builtin_amdgcn_rcpf(1.0f + __expf(-x));
}
__device__ __forceinline__ float tanhf_(float x) {
    return 2.0f * __builtin_amdgcn_rcpf(1.0f + __expf(-2.0f * x)) - 1.0f;
}

// H (32 rows x 256B) : XOR-swizzle 16B chunks by (b&7)
__device__ __forceinline__ int hswz(int b, int byteoff) {
    return b * 256 + ((byteoff & ~15) ^ ((b & 7) << 4)) + (byteoff & 15);
}
// gkT (32 rows x 1792B = 112 chunks of 16B)
__device__ __forceinline__ int gswz(int b, int chunk) {
    return b * 1792 + ((chunk ^ (b & 7)) << 4);
}

__global__ void prep_kernel(const float* __restrict__ Wr, const float* __restrict__ Wk,
                            unsigned short* __restrict__ Am, unsigned short* __restrict__ Ah,
                            unsigned short* __restrict__ Al) {
    int gid = blockIdx.x * 256 + threadIdx.x;   // 448*128 = 57344
    int r = gid >> 7, k = gid & 127;
    int u = r >> 2, g = r & 3;
    float wm = 0.f, wkv = 0.f;
    if (u < 100) {
        int col = g * 100 + u;
        if (k < 100)      { wm = Wr[k * 400 + col]; wkv = Wk[k * 400 + col]; }
        else if (k < 109) { wm = Wk[k * 400 + col]; }
    }
    unsigned short hi = f2bf(wkv);
    Am[gid] = f2bf(wm);
    Ah[gid] = hi;
    Al[gid] = f2bf(wkv - bf2f(hi));
}

__global__ __launch_bounds__(NT, 2) __attribute__((amdgpu_waves_per_eu(2, 2)))
void fwdsim_kernel(const float* __restrict__ sampled_z,
                   const float* __restrict__ idm_s,
                   const float* __restrict__ sdv_acts,
                   const float* __restrict__ W1, const float* __restrict__ b1,
                   const float* __restrict__ W2, const float* __restrict__ b2,
                   const float* __restrict__ bl, const float* __restrict__ Wd,
                   const float* __restrict__ bd,
                   const float* __restrict__ sc_mean, const float* __restrict__ sc_var,
                   const unsigned short* __restrict__ Am,
                   const unsigned short* __restrict__ Ah,
                   const unsigned short* __restrict__ Al,
                   float* __restrict__ out) {
    __shared__ char sm[SMEM_BYTES];
    float* gkT  = (float*)(sm + GKT_OFF);
    char*  Hhi  = sm + HHI_OFF;
    char*  Hlo  = sm + HLO_OFF;
    float* part = (float*)(sm + PART_OFF);
    float* W2s  = (float*)(sm + W2S_OFF);
    float* h1s  = (float*)(sm + H1S_OFF);
    float* projs= (float*)(sm + PROJ_OFF);

    const int tid = threadIdx.x;
    const int w = tid >> 6, l = tid & 63, lb = l & 15, lg = l >> 4;
    const int blk = blockIdx.x;

    // ---------------- init: stage W2 ; h1 = relu(z@W1+b1) ----------------
    for (int i = tid; i < 2500; i += NT) ((f32x4*)W2s)[i] = ((const f32x4*)W2)[i];
    {
        const int e = tid >> 3, q = tid & 7;       // 32 elems x 8 threads
        const int eg = blk * BT + e;
        float zv[6];
        #pragma unroll
        for (int r = 0; r < 6; ++r) zv[r] = sampled_z[eg * 6 + r];
        #pragma unroll
        for (int m = 0; m < 13; ++m) {
            const int c = q * 13 + m;
            if (c < 100) {
                float a = b1[c];
                #pragma unroll
                for (int r = 0; r < 6; ++r) a += zv[r] * W1[r * 100 + c];
                h1s[e * 100 + c] = fmaxf(a, 0.f);
            }
        }
    }
    __syncthreads();

    // ---------------- proj = relu(h1 @ W2 + b2) -> projs ----------------
    {
        const int e = tid >> 3, q = tid & 7;
        for (int m = 0; m < 13; ++m) {
            const int c = q * 13 + m;
            if (c < 100) {
                float a = b2[c];
                for (int k = 0; k < 100; ++k) a += h1s[e * 100 + k] * W2s[k * 100 + c];
                projs[e * 100 + c] = fmaxf(a, 0.f);
            }
        }
    }
    __syncthreads();

    // ---------------- register-stage projs (it aliases the H region) ----------------
    float hv_init[16];
    {
        const int b = tid >> 3, p = tid & 7;
        #pragma unroll
        for (int kk = 0; kk < 16; ++kk) {
            const int k = p * 16 + kk;
            hv_init[kk] = (k < 100) ? projs[b * 100 + k] : 0.f;
        }
    }
    float c_st[MT][NTL];
    float wd_reg[MT];
    #pragma unroll
    for (int m = 0; m < MT; ++m) {
        const int u = w * 28 + m * 4 + lg;
        wd_reg[m] = (u < 100) ? Wd[u] : 0.f;
        #pragma unroll
        for (int n = 0; n < NTL; ++n) {
            const int b = n * 16 + lb;
            c_st[m][n] = (u < 100) ? projs[b * 100 + u] : 0.f;
        }
    }
    __syncthreads();   // projs fully consumed

    // ---------------- H init (h0 = proj, rows 100..127 = 0) ----------------
    {
        const int b = tid >> 3, p = tid & 7;
        #pragma unroll
        for (int kk = 0; kk < 16; ++kk) {
            const int k = p * 16 + kk;
            const float v = hv_init[kk];
            const unsigned short hi = f2bf(v);
            const unsigned short lo = f2bf(v - bf2f(hi));
            const int off = hswz(b, 2 * k);
            *(unsigned short*)(Hhi + off) = hi;
            *(unsigned short*)(Hlo + off) = lo;
        }
    }
    // A-fragments (resident), scalers, env prefetch
    bf16x8 afr[MT][KC];
    #pragma unroll
    for (int m = 0; m < MT; ++m)
        #pragma unroll
        for (int kc = 0; kc < KC; ++kc) {
            const int row = w * 112 + m * 16 + lb;
            afr[m][kc] = *(const bf16x8*)(Am + row * 128 + kc * 32 + lg * 8);
        }
    float ms[7], is[7];
    #pragma unroll
    for (int r = 0; r < 7; ++r) { ms[r] = sc_mean[r]; is[r] = 1.0f / sqrtf(sc_var[r]); }
    const float bd0 = bd[0];
    const int b_env = (w & 1) * 16 + lb;
    const size_t eg_env = (size_t)(blk * BT + b_env);
    const bool env_owner = (w < 2) && (lg == 0);
    f32x4 cur0 = {0,0,0,0}, cur1 = {0,0,0,0}, cur2 = {0,0,0,0};
    f32x2 curs = {0,0};
    f32x4 nxt0 = {0,0,0,0}, nxt1 = {0,0,0,0}, nxt2 = {0,0,0,0};
    f32x2 nxts = {0,0};
    if (env_owner) {
        const float* ip = idm_s + (eg_env * TS + 0) * 12;
        cur0 = *(const f32x4*)ip; cur1 = *(const f32x4*)(ip + 4); cur2 = *(const f32x4*)(ip + 8);
        curs = *(const f32x2*)(sdv_acts + (eg_env * TS + 0) * 2);
    }
    __syncthreads();   // H ready

    // ---------------- gk = bl + WkT @ proj  (bf16x3 MFMA, fp32 -> gkT) ----------------
    {
        f32x4 acc[MT][NTL];
        #pragma unroll
        for (int m = 0; m < MT; ++m)
            #pragma unroll
            for (int n = 0; n < NTL; ++n) acc[m][n] = (f32x4){0.f, 0.f, 0.f, 0.f};
        for (int kc = 0; kc < KC; ++kc) {
            bf16x8 bhi[NTL], blo[NTL];
            #pragma unroll
            for (int n = 0; n < NTL; ++n) {
                const int b = n * 16 + lb;
                const int off = hswz(b, kc * 64 + lg * 16);
                bhi[n] = *(const bf16x8*)(Hhi + off);
                blo[n] = *(const bf16x8*)(Hlo + off);
            }
            bf16x8 ah[MT], al[MT];
            #pragma unroll
            for (int m = 0; m < MT; ++m) {
                const int row = w * 112 + m * 16 + lb;
                ah[m] = *(const bf16x8*)(Ah + row * 128 + kc * 32 + lg * 8);
                al[m] = *(const bf16x8*)(Al + row * 128 + kc * 32 + lg * 8);
            }
            // de-paired streams: chain distance MT*NTL between same-acc MFMAs
            #pragma unroll
            for (int m = 0; m < MT; ++m)
                #pragma unroll
                for (int n = 0; n < NTL; ++n)
                    acc[m][n] = __builtin_amdgcn_mfma_f32_16x16x32_bf16(ah[m], bhi[n], acc[m][n], 0, 0, 0);
            #pragma unroll
            for (int m = 0; m < MT; ++m)
                #pragma unroll
                for (int n = 0; n < NTL; ++n)
                    acc[m][n] = __builtin_amdgcn_mfma_f32_16x16x32_bf16(ah[m], blo[n], acc[m][n], 0, 0, 0);
            #pragma unroll
            for (int m = 0; m < MT; ++m)
                #pragma unroll
                for (int n = 0; n < NTL; ++n)
                    acc[m][n] = __builtin_amdgcn_mfma_f32_16x16x32_bf16(al[m], bhi[n], acc[m][n], 0, 0, 0);
        }
        #pragma unroll
        for (int m = 0; m < MT; ++m) {
            float blv[4];
            #pragma unroll
            for (int j = 0; j < 4; ++j) {
                const int row = w * 112 + m * 16 + lg * 4 + j;
                const int u = row >> 2, g = row & 3;
                blv[j] = (u < 100) ? bl[g * 100 + u] : 0.f;
            }
            const int chunk = w * 28 + m * 4 + lg;
            #pragma unroll
            for (int n = 0; n < NTL; ++n) {
                const int b = n * 16 + lb;
                f32x4 v = acc[m][n];
                v[0] += blv[0]; v[1] += blv[1]; v[2] += blv[2]; v[3] += blv[3];
                *(f32x4*)((char*)gkT + gswz(b, chunk)) = v;
            }
        }
    }
    __syncthreads();   // gkT ready

    // ---------------- main 40-step recurrence ----------------
    float ego_v = 0.f, ego_x = 0.f, prev_act = 0.f;
    for (int t = 0; t < TS; ++t) {
        // keep the A-fragments pinned in VGPRs (defeat rematerialization)
        #pragma unroll
        for (int m = 0; m < MT; ++m)
            #pragma unroll
            for (int kc = 0; kc < KC; ++kc)
                asm volatile("" : "+v"(afr[m][kc]));

        // A) env owners: x9(t) -> H rows 100..108 ; prefetch t+1
        if (env_owner) {
            if (t == 0) { ego_v = cur0[0]; ego_x = cur0[3]; }
            else {
                ego_v += prev_act * 0.1f;
                ego_x += ego_v * 0.1f + 0.005f * prev_act;
            }
            const float f_veh_v = cur0[1], m_veh_v = cur0[2];
            const float f_glob_x = cur1[0], m_glob_x = cur1[1];
            const float ef_dv_t = cur1[2], ef_dx_t = cur1[3];
            const float em_dv_t = cur2[0], em_dx_t = cur2[1];
            const float f_ex = cur2[2], m_ex = cur2[3];
            const float ef_dx = (f_glob_x - ego_x) * f_ex + (1.f - f_ex) * ef_dx_t;
            const float em_dx = (m_glob_x - ego_x) * m_ex + (1.f - m_ex) * em_dx_t;
            const float ef_dv = (ego_v - f_veh_v) * f_ex + (1.f - f_ex) * ef_dv_t;
            const float em_dv = (ego_v - m_veh_v) * m_ex + (1.f - m_ex) * em_dv_t;
            float x9[9];
            x9[0] = curs[0]; x9[1] = curs[1];
            x9[2] = (ego_v   - ms[0]) * is[0];
            x9[3] = (f_veh_v - ms[1]) * is[1];
            x9[4] = (m_veh_v - ms[2]) * is[2];
            x9[5] = (ef_dv   - ms[3]) * is[3];
            x9[6] = (ef_dx   - ms[4]) * is[4];
            x9[7] = (em_dv   - ms[5]) * is[5];
            x9[8] = (em_dx   - ms[6]) * is[6];
            #pragma unroll
            for (int r = 0; r < 9; ++r) {
                const unsigned short hi = f2bf(x9[r]);
                const int off = hswz(b_env, 200 + 2 * r);
                *(unsigned short*)(Hhi + off) = hi;
                *(unsigned short*)(Hlo + off) = f2bf(x9[r] - bf2f(hi));
            }
            if (t < TS - 1) {
                const float* ip = idm_s + (eg_env * TS + t + 1) * 12;
                nxt0 = *(const f32x4*)ip; nxt1 = *(const f32x4*)(ip + 4); nxt2 = *(const f32x4*)(ip + 8);
                nxts = *(const f32x2*)(sdv_acts + (eg_env * TS + t + 1) * 2);
            }
        }
        __syncthreads();   // B: x9 + h visible

        // C) z^T = gk + W_combT @ [h_hi+h_lo ; x9]
        f32x4 acc[MT][NTL];
        #pragma unroll
        for (int m = 0; m < MT; ++m) {
            const int chunk = w * 28 + m * 4 + lg;
            #pragma unroll
            for (int n = 0; n < NTL; ++n)
                acc[m][n] = *(const f32x4*)((const char*)gkT + gswz(n * 16 + lb, chunk));
        }
        #pragma unroll
        for (int kc = 0; kc < KC; ++kc) {
            bf16x8 bhi[NTL], blo[NTL];
            #pragma unroll
            for (int n = 0; n < NTL; ++n) {
                const int b = n * 16 + lb;
                const int off = hswz(b, kc * 64 + lg * 16);
                bhi[n] = *(const bf16x8*)(Hhi + off);
                blo[n] = *(const bf16x8*)(Hlo + off);
            }
            // de-paired: all hi-stream MFMAs, then all lo-stream
            #pragma unroll
            for (int m = 0; m < MT; ++m)
                #pragma unroll
                for (int n = 0; n < NTL; ++n)
                    acc[m][n] = __builtin_amdgcn_mfma_f32_16x16x32_bf16(afr[m][kc], bhi[n], acc[m][n], 0, 0, 0);
            #pragma unroll
            for (int m = 0; m < MT; ++m)
                #pragma unroll
                for (int n = 0; n < NTL; ++n)
                    acc[m][n] = __builtin_amdgcn_mfma_f32_16x16x32_bf16(afr[m][kc], blo[n], acc[m][n], 0, 0, 0);
        }
        __syncthreads();   // D: all H reads done before h(t+1) writes

        // E) gates in-register; h -> LDS ; act partials
        float pact[NTL] = {0.f, 0.f};
        #pragma unroll
        for (int m = 0; m < MT; ++m) {
            const int u = w * 28 + m * 4 + lg;
            #pragma unroll
            for (int n = 0; n < NTL; ++n) {
                const int b = n * 16 + lb;
                f32x4 z = acc[m][n];
                const float cc = sigf(z[1]) * c_st[m][n] + sigf(z[0]) * tanhf_(z[2]);
                const float hh = sigf(z[3]) * tanhf_(cc);
                c_st[m][n] = cc;
                pact[n] += hh * wd_reg[m];
                if (u < 100) {
                    const unsigned short hi = f2bf(hh);
                    const int off = hswz(b, 2 * u);
                    *(unsigned short*)(Hhi + off) = hi;
                    *(unsigned short*)(Hlo + off) = f2bf(hh - bf2f(hi));
                }
            }
        }
        #pragma unroll
        for (int n = 0; n < NTL; ++n) {
            float p = pact[n];
            p += __shfl_xor(p, 16);
            p += __shfl_xor(p, 32);
            if (l < 16) part[w * 32 + n * 16 + l] = p;
        }
        __syncthreads();   // F: part + h visible

        // G) act = sum over 4 waves + bd ; output ; advance prefetch
        if (env_owner) {
            const float act = part[b_env] + part[32 + b_env] + part[64 + b_env] + part[96 + b_env] + bd0;
            out[eg_env * TS + t] = act;
            prev_act = act;
            if (t < TS - 1) { cur0 = nxt0; cur1 = nxt1; cur2 = nxt2; curs = nxts; }
        }
    }
}

extern "C" void kernel_launch(void* const* d_in, const int* in_sizes, int n_in,
                              void* d_out, int out_size, void* d_ws, size_t ws_size,
                              hipStream_t stream) {
    const float* sampled_z = (const float*)d_in[0];
    const float* idm_s     = (const float*)d_in[1];
    const float* sdv_acts  = (const float*)d_in[2];
    const float* W1        = (const float*)d_in[3];
    const float* b1        = (const float*)d_in[4];
    const float* W2        = (const float*)d_in[5];
    const float* b2        = (const float*)d_in[6];
    const float* Wk        = (const float*)d_in[7];
    const float* Wr        = (const float*)d_in[8];
    const float* bl        = (const float*)d_in[9];
    const float* Wd        = (const float*)d_in[10];
    const float* bd        = (const float*)d_in[11];
    const float* sc_mean   = (const float*)d_in[12];
    const float* sc_var    = (const float*)d_in[13];
    float* out = (float*)d_out;

    unsigned short* Am = (unsigned short*)d_ws;       // [448][128] bf16
    unsigned short* Ah = Am + 448 * 128;              // Wk-proj hi
    unsigned short* Al = Ah + 448 * 128;              // Wk-proj lo

    hipLaunchKernelGGL(prep_kernel, dim3(224), dim3(256), 0, stream, Wr, Wk, Am, Ah, Al);
    hipLaunchKernelGGL(fwdsim_kernel, dim3(16384 / BT), dim3(NT), 0, stream,
                       sampled_z, idm_s, sdv_acts, W1, b1, W2, b2, bl, Wd, bd,
                       sc_mean, sc_var, Am, Ah, Al, out);
}

// Round 10
// 271.482 us; speedup vs baseline: 1.7698x; 1.5468x over previous
//
#include <hip/hip_runtime.h>

#define TS 40
#define BT 32
#define NT 512
#define MT 7      // m-tiles of 16 rows per wave-row ; M = 448 = 112 units * 4 gates
#define KC 4      // k-chunks of 32 ; K = 128 (100 h + 9 env + pad)

typedef short bf16x8 __attribute__((ext_vector_type(8)));
typedef float f32x4 __attribute__((ext_vector_type(4)));
typedef float f32x2 __attribute__((ext_vector_type(2)));

// LDS map (147968 B, 1 block/CU, 8 waves):
//  [0,114688)        As: W_comb bf16 [448][128], 16B-chunk XOR swizzle
//  [114688,147456)   H buffers: buf0{hi@114688,lo@122880} buf1{hi@131072,lo@139264}
//  [147456,147968)   part f32[4][32]
//  init aliases (inside As, consumed before As staged):
//    W2s@0 (40000) ; h1s@40000 (12800) ; projs@52800 (12800)
#define AS_OFF   0
#define HB_OFF   114688
#define PART_OFF 147456
#define W2S_OFF  0
#define H1S_OFF  40000
#define PROJ_OFF 52800
#define SMEM_BYTES 147968

__device__ __forceinline__ unsigned short f2bf(float x) {
    unsigned u = __float_as_uint(x);
    unsigned r = u + 0x7fffu + ((u >> 16) & 1u);
    return (unsigned short)(r >> 16);
}
__device__ __forceinline__ float bf2f(unsigned short s) {
    return __uint_as_float(((unsigned)s) << 16);
}
// v_rcp_f32-based (1 ulp) -- avoids IEEE divide expansion
__device__ __forceinline__ float sigf(float x) {
    return __builtin_amdgcn_rcpf(1.0f + __expf(-x));
}
__device__ __forceinline__ float tanhf_(float x) {
    return 2.0f * __builtin_amdgcn_rcpf(1.0f + __expf(-2.0f * x)) - 1.0f;
}

// H row (256B) : XOR-swizzle 16B chunks by (b&7)
__device__ __forceinline__ int hswz(int b, int byteoff) {
    return b * 256 + ((byteoff & ~15) ^ ((b & 7) << 4)) + (byteoff & 15);
}
// As row (256B) : byteoff16 must be 16B aligned
__device__ __forceinline__ int aswz(int row, int byteoff16) {
    return row * 256 + (byteoff16 ^ ((row & 7) << 4));
}

__global__ void prep_kernel(const float* __restrict__ Wr, const float* __restrict__ Wk,
                            unsigned short* __restrict__ Am, unsigned short* __restrict__ Ah,
                            unsigned short* __restrict__ Al) {
    int gid = blockIdx.x * 256 + threadIdx.x;   // 448*128 = 57344
    int r = gid >> 7, k = gid & 127;
    int u = r >> 2, g = r & 3;
    float wm = 0.f, wkv = 0.f;
    if (u < 100) {
        int col = g * 100 + u;
        if (k < 100)      { wm = Wr[k * 400 + col]; wkv = Wk[k * 400 + col]; }
        else if (k < 109) { wm = Wk[k * 400 + col]; }
    }
    unsigned short hi = f2bf(wkv);
    Am[gid] = f2bf(wm);
    Ah[gid] = hi;
    Al[gid] = f2bf(wkv - bf2f(hi));
}

__global__ __launch_bounds__(NT, 2)
void fwdsim_kernel(const float* __restrict__ sampled_z,
                   const float* __restrict__ idm_s,
                   const float* __restrict__ sdv_acts,
                   const float* __restrict__ W1, const float* __restrict__ b1,
                   const float* __restrict__ W2, const float* __restrict__ b2,
                   const float* __restrict__ bl, const float* __restrict__ Wd,
                   const float* __restrict__ bd,
                   const float* __restrict__ sc_mean, const float* __restrict__ sc_var,
                   const unsigned short* __restrict__ Am,
                   const unsigned short* __restrict__ Ah,
                   const unsigned short* __restrict__ Al,
                   float* __restrict__ out) {
    __shared__ char sm[SMEM_BYTES];
    char*  As   = sm + AS_OFF;
    float* part = (float*)(sm + PART_OFF);
    float* W2s  = (float*)(sm + W2S_OFF);
    float* h1s  = (float*)(sm + H1S_OFF);
    float* projs= (float*)(sm + PROJ_OFF);

    const int tid = threadIdx.x;
    const int w = tid >> 6, l = tid & 63, lb = l & 15, lg = l >> 4;
    const int wm = w >> 1, wn = w & 1;
    const int blk = blockIdx.x;
    const int b = wn * 16 + lb;            // batch col (0..31) for MFMA frags

    // ---------------- init: stage W2 ; h1 = relu(z@W1+b1) ----------------
    for (int i = tid; i < 2500; i += NT) ((f32x4*)W2s)[i] = ((const f32x4*)W2)[i];
    {
        const int e = tid >> 4, q = tid & 15;      // 32 elems x 16 threads
        const int eg = blk * BT + e;
        float zv[6];
        #pragma unroll
        for (int r = 0; r < 6; ++r) zv[r] = sampled_z[eg * 6 + r];
        #pragma unroll
        for (int m = 0; m < 7; ++m) {
            const int c = q * 7 + m;
            if (c < 100) {
                float a = b1[c];
                #pragma unroll
                for (int r = 0; r < 6; ++r) a += zv[r] * W1[r * 100 + c];
                h1s[e * 100 + c] = fmaxf(a, 0.f);
            }
        }
    }
    __syncthreads();

    // ---------------- proj = relu(h1 @ W2 + b2) -> projs ----------------
    {
        const int e = tid >> 4, q = tid & 15;
        for (int m = 0; m < 7; ++m) {
            const int c = q * 7 + m;
            if (c < 100) {
                float a = b2[c];
                for (int k = 0; k < 100; ++k) a += h1s[e * 100 + k] * W2s[k * 100 + c];
                projs[e * 100 + c] = fmaxf(a, 0.f);
            }
        }
    }
    __syncthreads();

    // ---------------- register-stage projs (As staging will overwrite it) ----------------
    float hv_init[8];
    {
        const int bi = tid >> 4, p = tid & 15;
        #pragma unroll
        for (int kk = 0; kk < 8; ++kk) {
            const int k = p * 8 + kk;
            hv_init[kk] = (k < 100) ? projs[bi * 100 + k] : 0.f;
        }
    }
    float c_st[MT], wd_reg[MT];
    #pragma unroll
    for (int m = 0; m < MT; ++m) {
        const int u = wm * 28 + m * 4 + lg;
        wd_reg[m] = (u < 100) ? Wd[u] : 0.f;
        c_st[m]   = (u < 100) ? projs[b * 100 + u] : 0.f;
    }
    __syncthreads();   // projs fully consumed

    // ---------------- H0 init + buf1 ZERO + As staging ----------------
    {
        char* Hhi0 = sm + HB_OFF;
        char* Hlo0 = Hhi0 + 8192;
        const int bi = tid >> 4, p = tid & 15;
        #pragma unroll
        for (int kk = 0; kk < 8; ++kk) {
            const int k = p * 8 + kk;
            const float v = hv_init[kk];
            const unsigned short hi = f2bf(v);
            const int off = hswz(bi, 2 * k);
            *(unsigned short*)(Hhi0 + off) = hi;
            *(unsigned short*)(Hlo0 + off) = f2bf(v - bf2f(hi));
        }
        // zero ALL of buf1 (hi+lo): stale LDS here can decode to Inf/NaN bf16;
        // 0 * Inf = NaN in the MFMA even though A-cols 109..127 are zero (R9 bug).
        f32x4 z4 = {0.f, 0.f, 0.f, 0.f};
        f32x4* B1 = (f32x4*)(sm + HB_OFF + 16384);
        B1[tid]       = z4;
        B1[tid + 512] = z4;     // 1024 * 16B = 16384 B
    }
    #pragma unroll
    for (int i = 0; i < 14; ++i) {            // 7168 16B chunks
        const int ch = tid + i * NT;
        const int row = ch >> 4, c = ch & 15;
        *(bf16x8*)(As + aswz(row, c * 16)) = *(const bf16x8*)(Am + row * 128 + c * 8);
    }
    float ms[7], is[7];
    #pragma unroll
    for (int r = 0; r < 7; ++r) { ms[r] = sc_mean[r]; is[r] = 1.0f / sqrtf(sc_var[r]); }
    const float bd0 = bd[0];
    const bool env_owner = (w < 2) && (lg == 0);
    const size_t eg_env = (size_t)(blk * BT + b);
    __syncthreads();   // H0 + buf1-zero + As ready

    // ---------------- x9(0) -> H0 rows 100..108 ; prefetch idm(1) ----------------
    float ego_v = 0.f, ego_x = 0.f;
    f32x4 cur0 = {0,0,0,0}, cur1 = {0,0,0,0}, cur2 = {0,0,0,0};
    f32x2 curs = {0,0};
    if (env_owner) {
        char* Hhi0 = sm + HB_OFF;
        char* Hlo0 = Hhi0 + 8192;
        const float* ip = idm_s + (eg_env * TS + 0) * 12;
        f32x4 i0 = *(const f32x4*)ip, i1 = *(const f32x4*)(ip + 4), i2 = *(const f32x4*)(ip + 8);
        f32x2 s0 = *(const f32x2*)(sdv_acts + (eg_env * TS + 0) * 2);
        ego_v = i0[0]; ego_x = i0[3];
        const float f_veh_v = i0[1], m_veh_v = i0[2];
        const float f_glob_x = i1[0], m_glob_x = i1[1];
        const float ef_dv_t = i1[2], ef_dx_t = i1[3];
        const float em_dv_t = i2[0], em_dx_t = i2[1];
        const float f_ex = i2[2], m_ex = i2[3];
        const float ef_dx = (f_glob_x - ego_x) * f_ex + (1.f - f_ex) * ef_dx_t;
        const float em_dx = (m_glob_x - ego_x) * m_ex + (1.f - m_ex) * em_dx_t;
        const float ef_dv = (ego_v - f_veh_v) * f_ex + (1.f - f_ex) * ef_dv_t;
        const float em_dv = (ego_v - m_veh_v) * m_ex + (1.f - m_ex) * em_dv_t;
        float x9[9];
        x9[0] = s0[0]; x9[1] = s0[1];
        x9[2] = (ego_v   - ms[0]) * is[0];
        x9[3] = (f_veh_v - ms[1]) * is[1];
        x9[4] = (m_veh_v - ms[2]) * is[2];
        x9[5] = (ef_dv   - ms[3]) * is[3];
        x9[6] = (ef_dx   - ms[4]) * is[4];
        x9[7] = (em_dv   - ms[5]) * is[5];
        x9[8] = (em_dx   - ms[6]) * is[6];
        #pragma unroll
        for (int r = 0; r < 9; ++r) {
            const unsigned short hi = f2bf(x9[r]);
            const int off = hswz(b, 200 + 2 * r);
            *(unsigned short*)(Hhi0 + off) = hi;
            *(unsigned short*)(Hlo0 + off) = f2bf(x9[r] - bf2f(hi));
        }
        const float* ip1 = idm_s + (eg_env * TS + 1) * 12;
        cur0 = *(const f32x4*)ip1; cur1 = *(const f32x4*)(ip1 + 4); cur2 = *(const f32x4*)(ip1 + 8);
        curs = *(const f32x2*)(sdv_acts + (eg_env * TS + 1) * 2);
    }

    // ---------------- gk = bl + WkT @ proj  (A from global Ah/Al; B = H0) ----------------
    f32x4 gk[MT];
    {
        char* Hhi0 = sm + HB_OFF;
        char* Hlo0 = Hhi0 + 8192;
        #pragma unroll
        for (int m = 0; m < MT; ++m) gk[m] = (f32x4){0.f, 0.f, 0.f, 0.f};
        for (int kc = 0; kc < KC; ++kc) {
            const int off = hswz(b, kc * 64 + lg * 16);
            bf16x8 bhi = *(const bf16x8*)(Hhi0 + off);
            bf16x8 blo = *(const bf16x8*)(Hlo0 + off);
            bf16x8 ah[MT], al[MT];
            #pragma unroll
            for (int m = 0; m < MT; ++m) {
                const int row = wm * 112 + m * 16 + lb;
                ah[m] = *(const bf16x8*)(Ah + row * 128 + kc * 32 + lg * 8);
                al[m] = *(const bf16x8*)(Al + row * 128 + kc * 32 + lg * 8);
            }
            #pragma unroll
            for (int m = 0; m < MT; ++m)
                gk[m] = __builtin_amdgcn_mfma_f32_16x16x32_bf16(ah[m], bhi, gk[m], 0, 0, 0);
            #pragma unroll
            for (int m = 0; m < MT; ++m)
                gk[m] = __builtin_amdgcn_mfma_f32_16x16x32_bf16(ah[m], blo, gk[m], 0, 0, 0);
            #pragma unroll
            for (int m = 0; m < MT; ++m)
                gk[m] = __builtin_amdgcn_mfma_f32_16x16x32_bf16(al[m], bhi, gk[m], 0, 0, 0);
        }
        #pragma unroll
        for (int m = 0; m < MT; ++m) {
            #pragma unroll
            for (int j = 0; j < 4; ++j) {
                const int row = wm * 112 + m * 16 + lg * 4 + j;
                const int u = row >> 2, g = row & 3;
                gk[m][j] += (u < 100) ? bl[g * 100 + u] : 0.f;
            }
        }
    }
    __syncthreads();   // x9(0) visible; ready for the loop

    // ---------------- main 40-step recurrence (2 barriers/step) ----------------
    int cb = 0;
    for (int t = 0; t < TS; ++t) {
        char* Hhi_c = sm + HB_OFF + cb * 16384;
        char* Hlo_c = Hhi_c + 8192;
        char* Hhi_n = sm + HB_OFF + (cb ^ 1) * 16384;
        char* Hlo_n = Hhi_n + 8192;

        // C) z^T = gk + W_comb @ [h ; x9]   (A from LDS, B = H_cur)
        f32x4 acc[MT];
        #pragma unroll
        for (int m = 0; m < MT; ++m) acc[m] = gk[m];
        #pragma unroll
        for (int kc = 0; kc < KC; ++kc) {
            const int off = hswz(b, kc * 64 + lg * 16);
            bf16x8 bhi = *(const bf16x8*)(Hhi_c + off);
            bf16x8 blo = *(const bf16x8*)(Hlo_c + off);
            bf16x8 a[MT];
            #pragma unroll
            for (int m = 0; m < MT; ++m) {
                const int row = wm * 112 + m * 16 + lb;
                a[m] = *(const bf16x8*)(As + aswz(row, kc * 64 + lg * 16));
            }
            #pragma unroll
            for (int m = 0; m < MT; ++m)
                acc[m] = __builtin_amdgcn_mfma_f32_16x16x32_bf16(a[m], bhi, acc[m], 0, 0, 0);
            #pragma unroll
            for (int m = 0; m < MT; ++m)
                acc[m] = __builtin_amdgcn_mfma_f32_16x16x32_bf16(a[m], blo, acc[m], 0, 0, 0);
        }

        // E) gates in-register ; h(t+1) -> H_next ; act partials
        float pact = 0.f;
        #pragma unroll
        for (int m = 0; m < MT; ++m) {
            const int u = wm * 28 + m * 4 + lg;
            f32x4 z = acc[m];
            const float cc = sigf(z[1]) * c_st[m] + sigf(z[0]) * tanhf_(z[2]);
            const float hh = sigf(z[3]) * tanhf_(cc);
            c_st[m] = cc;
            pact += hh * wd_reg[m];
            if (u < 100) {
                const unsigned short hi = f2bf(hh);
                const int off = hswz(b, 2 * u);
                *(unsigned short*)(Hhi_n + off) = hi;
                *(unsigned short*)(Hlo_n + off) = f2bf(hh - bf2f(hi));
            }
        }
        pact += __shfl_xor(pact, 16);
        pact += __shfl_xor(pact, 32);
        if (l < 16) part[wm * 32 + wn * 16 + l] = pact;
        __syncthreads();   // part + h(t+1) visible

        // G) act ; output ; x9(t+1) -> H_next ; advance idm prefetch
        if (env_owner) {
            const float act = part[b] + part[32 + b] + part[64 + b] + part[96 + b] + bd0;
            out[eg_env * TS + t] = act;
            if (t < TS - 1) {
                ego_v += act * 0.1f;
                ego_x += ego_v * 0.1f + 0.005f * act;
                const float f_veh_v = cur0[1], m_veh_v = cur0[2];
                const float f_glob_x = cur1[0], m_glob_x = cur1[1];
                const float ef_dv_t = cur1[2], ef_dx_t = cur1[3];
                const float em_dv_t = cur2[0], em_dx_t = cur2[1];
                const float f_ex = cur2[2], m_ex = cur2[3];
                const float ef_dx = (f_glob_x - ego_x) * f_ex + (1.f - f_ex) * ef_dx_t;
                const float em_dx = (m_glob_x - ego_x) * m_ex + (1.f - m_ex) * em_dx_t;
                const float ef_dv = (ego_v - f_veh_v) * f_ex + (1.f - f_ex) * ef_dv_t;
                const float em_dv = (ego_v - m_veh_v) * m_ex + (1.f - m_ex) * em_dv_t;
                float x9[9];
                x9[0] = curs[0]; x9[1] = curs[1];
                x9[2] = (ego_v   - ms[0]) * is[0];
                x9[3] = (f_veh_v - ms[1]) * is[1];
                x9[4] = (m_veh_v - ms[2]) * is[2];
                x9[5] = (ef_dv   - ms[3]) * is[3];
                x9[6] = (ef_dx   - ms[4]) * is[4];
                x9[7] = (em_dv   - ms[5]) * is[5];
                x9[8] = (em_dx   - ms[6]) * is[6];
                #pragma unroll
                for (int r = 0; r < 9; ++r) {
                    const unsigned short hi = f2bf(x9[r]);
                    const int off = hswz(b, 200 + 2 * r);
                    *(unsigned short*)(Hhi_n + off) = hi;
                    *(unsigned short*)(Hlo_n + off) = f2bf(x9[r] - bf2f(hi));
                }
                if (t < TS - 2) {
                    const float* ip = idm_s + (eg_env * TS + t + 2) * 12;
                    cur0 = *(const f32x4*)ip; cur1 = *(const f32x4*)(ip + 4); cur2 = *(const f32x4*)(ip + 8);
                    curs = *(const f32x2*)(sdv_acts + (eg_env * TS + t + 2) * 2);
                }
            }
        }
        __syncthreads();   // H_next complete
        cb ^= 1;
    }
}

extern "C" void kernel_launch(void* const* d_in, const int* in_sizes, int n_in,
                              void* d_out, int out_size, void* d_ws, size_t ws_size,
                              hipStream_t stream) {
    const float* sampled_z = (const float*)d_in[0];
    const float* idm_s     = (const float*)d_in[1];
    const float* sdv_acts  = (const float*)d_in[2];
    const float* W1        = (const float*)d_in[3];
    const float* b1        = (const float*)d_in[4];
    const float* W2        = (const float*)d_in[5];
    const float* b2        = (const float*)d_in[6];
    const float* Wk        = (const float*)d_in[7];
    const float* Wr        = (const float*)d_in[8];
    const float* bl        = (const float*)d_in[9];
    const float* Wd        = (const float*)d_in[10];
    const float* bd        = (const float*)d_in[11];
    const float* sc_mean   = (const float*)d_in[12];
    const float* sc_var    = (const float*)d_in[13];
    float* out = (float*)d_out;

    unsigned short* Am = (unsigned short*)d_ws;       // [448][128] bf16: Wr + Wk-env
    unsigned short* Ah = Am + 448 * 128;              // Wk[0:100] hi
    unsigned short* Al = Ah + 448 * 128;              // Wk[0:100] lo

    hipLaunchKernelGGL(prep_kernel, dim3(224), dim3(256), 0, stream, Wr, Wk, Am, Ah, Al);
    hipLaunchKernelGGL(fwdsim_kernel, dim3(16384 / BT), dim3(NT), 0, stream,
                       sampled_z, idm_s, sdv_acts, W1, b1, W2, b2, bl, Wd, bd,
                       sc_mean, sc_var, Am, Ah, Al, out);
}

// Round 12
// 259.533 us; speedup vs baseline: 1.8513x; 1.0460x over previous
//
#include <hip/hip_runtime.h>

#define TS 40
#define BT 32
#define NT 512
#define MT 7      // m-tiles of 16 rows per wave-row ; M = 448 = 112 units * 4 gates
#define KC 4      // k-chunks of 32 ; K = 128 (100 h + 9 env + pad)

typedef short bf16x8 __attribute__((ext_vector_type(8)));
typedef float f32x4 __attribute__((ext_vector_type(4)));
typedef float f32x2 __attribute__((ext_vector_type(2)));

// LDS map (98880 B, 1 block/CU, 8 waves):
//  [0,65600)        init scratch: W2s@0 (40000) ; h1s@40000 (12800) ; projs@52800 (12800)
//  [65600,98368)    H buffers: buf0{hi@65600,lo@73792} buf1{hi@81984,lo@90176}
//  [98368,98880)    part f32[4][32]
//  A-matrix (W_comb) lives in REGISTERS (28 bf16x8 frags/wave), not LDS.
#define W2S_OFF  0
#define H1S_OFF  40000
#define PROJ_OFF 52800
#define HB_OFF   65600
#define PART_OFF 98368
#define SMEM_BYTES 98880

__device__ __forceinline__ unsigned short f2bf(float x) {
    unsigned u = __float_as_uint(x);
    unsigned r = u + 0x7fffu + ((u >> 16) & 1u);
    return (unsigned short)(r >> 16);
}
__device__ __forceinline__ float bf2f(unsigned short s) {
    return __uint_as_float(((unsigned)s) << 16);
}
// v_rcp_f32-based (1 ulp) -- avoids IEEE divide expansion
__device__ __forceinline__ float sigf(float x) {
    return __builtin_amdgcn_rcpf(1.0f + __expf(-x));
}
__device__ __forceinline__ float tanhf_(float x) {
    return 2.0f * __builtin_amdgcn_rcpf(1.0f + __expf(-2.0f * x)) - 1.0f;
}

// H row (256B) : XOR-swizzle 16B chunks by (b&7)
__device__ __forceinline__ int hswz(int b, int byteoff) {
    return b * 256 + ((byteoff & ~15) ^ ((b & 7) << 4)) + (byteoff & 15);
}

__global__ void prep_kernel(const float* __restrict__ Wr, const float* __restrict__ Wk,
                            unsigned short* __restrict__ Am, unsigned short* __restrict__ Ah,
                            unsigned short* __restrict__ Al) {
    int gid = blockIdx.x * 256 + threadIdx.x;   // 448*128 = 57344
    int r = gid >> 7, k = gid & 127;
    int u = r >> 2, g = r & 3;
    float wm = 0.f, wkv = 0.f;
    if (u < 100) {
        int col = g * 100 + u;
        if (k < 100)      { wm = Wr[k * 400 + col]; wkv = Wk[k * 400 + col]; }
        else if (k < 109) { wm = Wk[k * 400 + col]; }
    }
    unsigned short hi = f2bf(wkv);
    Am[gid] = f2bf(wm);
    Ah[gid] = hi;
    Al[gid] = f2bf(wkv - bf2f(hi));
}

__global__ __launch_bounds__(NT, 2)
void fwdsim_kernel(const float* __restrict__ sampled_z,
                   const float* __restrict__ idm_s,
                   const float* __restrict__ sdv_acts,
                   const float* __restrict__ W1, const float* __restrict__ b1,
                   const float* __restrict__ W2, const float* __restrict__ b2,
                   const float* __restrict__ bl, const float* __restrict__ Wd,
                   const float* __restrict__ bd,
                   const float* __restrict__ sc_mean, const float* __restrict__ sc_var,
                   const unsigned short* __restrict__ Am,
                   const unsigned short* __restrict__ Ah,
                   const unsigned short* __restrict__ Al,
                   float* __restrict__ out) {
    __shared__ char sm[SMEM_BYTES];
    float* part = (float*)(sm + PART_OFF);
    float* W2s  = (float*)(sm + W2S_OFF);
    float* h1s  = (float*)(sm + H1S_OFF);
    float* projs= (float*)(sm + PROJ_OFF);

    const int tid = threadIdx.x;
    const int w = tid >> 6, l = tid & 63, lb = l & 15, lg = l >> 4;
    const int wm = w >> 1, wn = w & 1;
    const int blk = blockIdx.x;
    const int b = wn * 16 + lb;            // batch col (0..31) for MFMA frags

    // ---------------- init: stage W2 ; h1 = relu(z@W1+b1) ----------------
    for (int i = tid; i < 2500; i += NT) ((f32x4*)W2s)[i] = ((const f32x4*)W2)[i];
    {
        const int e = tid >> 4, q = tid & 15;      // 32 elems x 16 threads
        const int eg = blk * BT + e;
        float zv[6];
        #pragma unroll
        for (int r = 0; r < 6; ++r) zv[r] = sampled_z[eg * 6 + r];
        #pragma unroll
        for (int m = 0; m < 7; ++m) {
            const int c = q * 7 + m;
            if (c < 100) {
                float a = b1[c];
                #pragma unroll
                for (int r = 0; r < 6; ++r) a += zv[r] * W1[r * 100 + c];
                h1s[e * 100 + c] = fmaxf(a, 0.f);
            }
        }
    }
    __syncthreads();

    // ---------------- proj = relu(h1 @ W2 + b2) -> projs ----------------
    {
        const int e = tid >> 4, q = tid & 15;
        for (int m = 0; m < 7; ++m) {
            const int c = q * 7 + m;
            if (c < 100) {
                float a = b2[c];
                for (int k = 0; k < 100; ++k) a += h1s[e * 100 + k] * W2s[k * 100 + c];
                projs[e * 100 + c] = fmaxf(a, 0.f);
            }
        }
    }
    __syncthreads();

    // ---------------- per-thread state from projs ----------------
    float c_st[MT], wd_reg[MT];
    #pragma unroll
    for (int m = 0; m < MT; ++m) {
        const int u = wm * 28 + m * 4 + lg;
        wd_reg[m] = (u < 100) ? Wd[u] : 0.f;
        c_st[m]   = (u < 100) ? projs[b * 100 + u] : 0.f;
    }

    // ---------------- H0 init (h0 = proj, rows 100..127 = 0) + buf1 ZERO ----------------
    {
        char* Hhi0 = sm + HB_OFF;
        char* Hlo0 = Hhi0 + 8192;
        const int bi = tid >> 4, p = tid & 15;
        #pragma unroll
        for (int kk = 0; kk < 8; ++kk) {
            const int k = p * 8 + kk;
            const float v = (k < 100) ? projs[bi * 100 + k] : 0.f;
            const unsigned short hi = f2bf(v);
            const int off = hswz(bi, 2 * k);
            *(unsigned short*)(Hhi0 + off) = hi;
            *(unsigned short*)(Hlo0 + off) = f2bf(v - bf2f(hi));
        }
        // zero ALL of buf1 (hi+lo): stale LDS can decode to Inf/NaN bf16 and
        // 0 * Inf = NaN in the MFMA (R9 lesson).
        f32x4 z4 = {0.f, 0.f, 0.f, 0.f};
        f32x4* B1 = (f32x4*)(sm + HB_OFF + 16384);
        B1[tid]       = z4;
        B1[tid + 512] = z4;     // 1024 * 16B = 16384 B
    }

    // ---------------- resident A-fragments: 28 bf16x8 = 112 VGPR ----------------
    bf16x8 afr[MT][KC];
    #pragma unroll
    for (int m = 0; m < MT; ++m)
        #pragma unroll
        for (int kc = 0; kc < KC; ++kc) {
            const int row = wm * 112 + m * 16 + lb;
            afr[m][kc] = *(const bf16x8*)(Am + row * 128 + kc * 32 + lg * 8);
        }

    float ms[7], is[7];
    #pragma unroll
    for (int r = 0; r < 7; ++r) { ms[r] = sc_mean[r]; is[r] = 1.0f / sqrtf(sc_var[r]); }
    const float bd0 = bd[0];
    const bool env_owner = (w < 2) && (lg == 0);
    const size_t eg_env = (size_t)(blk * BT + b);
    __syncthreads();   // H0 + buf1-zero ready

    // ---------------- x9(0) -> H0 rows 100..108 ; prefetch idm(1) ----------------
    float ego_v = 0.f, ego_x = 0.f;
    f32x4 cur0 = {0,0,0,0}, cur1 = {0,0,0,0}, cur2 = {0,0,0,0};
    f32x2 curs = {0,0};
    if (env_owner) {
        char* Hhi0 = sm + HB_OFF;
        char* Hlo0 = Hhi0 + 8192;
        const float* ip = idm_s + (eg_env * TS + 0) * 12;
        f32x4 i0 = *(const f32x4*)ip, i1 = *(const f32x4*)(ip + 4), i2 = *(const f32x4*)(ip + 8);
        f32x2 s0 = *(const f32x2*)(sdv_acts + (eg_env * TS + 0) * 2);
        ego_v = i0[0]; ego_x = i0[3];
        const float f_veh_v = i0[1], m_veh_v = i0[2];
        const float f_glob_x = i1[0], m_glob_x = i1[1];
        const float ef_dv_t = i1[2], ef_dx_t = i1[3];
        const float em_dv_t = i2[0], em_dx_t = i2[1];
        const float f_ex = i2[2], m_ex = i2[3];
        const float ef_dx = (f_glob_x - ego_x) * f_ex + (1.f - f_ex) * ef_dx_t;
        const float em_dx = (m_glob_x - ego_x) * m_ex + (1.f - m_ex) * em_dx_t;
        const float ef_dv = (ego_v - f_veh_v) * f_ex + (1.f - f_ex) * ef_dv_t;
        const float em_dv = (ego_v - m_veh_v) * m_ex + (1.f - m_ex) * em_dv_t;
        float x9[9];
        x9[0] = s0[0]; x9[1] = s0[1];
        x9[2] = (ego_v   - ms[0]) * is[0];
        x9[3] = (f_veh_v - ms[1]) * is[1];
        x9[4] = (m_veh_v - ms[2]) * is[2];
        x9[5] = (ef_dv   - ms[3]) * is[3];
        x9[6] = (ef_dx   - ms[4]) * is[4];
        x9[7] = (em_dv   - ms[5]) * is[5];
        x9[8] = (em_dx   - ms[6]) * is[6];
        #pragma unroll
        for (int r = 0; r < 9; ++r) {
            const unsigned short hi = f2bf(x9[r]);
            const int off = hswz(b, 200 + 2 * r);
            *(unsigned short*)(Hhi0 + off) = hi;
            *(unsigned short*)(Hlo0 + off) = f2bf(x9[r] - bf2f(hi));
        }
        const float* ip1 = idm_s + (eg_env * TS + 1) * 12;
        cur0 = *(const f32x4*)ip1; cur1 = *(const f32x4*)(ip1 + 4); cur2 = *(const f32x4*)(ip1 + 8);
        curs = *(const f32x2*)(sdv_acts + (eg_env * TS + 1) * 2);
    }

    // ---------------- gk = bl + WkT @ proj  (A from global Ah/Al; B = H0) ----------------
    f32x4 gk[MT];
    {
        char* Hhi0 = sm + HB_OFF;
        char* Hlo0 = Hhi0 + 8192;
        #pragma unroll
        for (int m = 0; m < MT; ++m) gk[m] = (f32x4){0.f, 0.f, 0.f, 0.f};
        for (int kc = 0; kc < KC; ++kc) {
            const int off = hswz(b, kc * 64 + lg * 16);
            bf16x8 bhi = *(const bf16x8*)(Hhi0 + off);
            bf16x8 blo = *(const bf16x8*)(Hlo0 + off);
            bf16x8 ah[MT], al[MT];
            #pragma unroll
            for (int m = 0; m < MT; ++m) {
                const int row = wm * 112 + m * 16 + lb;
                ah[m] = *(const bf16x8*)(Ah + row * 128 + kc * 32 + lg * 8);
                al[m] = *(const bf16x8*)(Al + row * 128 + kc * 32 + lg * 8);
            }
            #pragma unroll
            for (int m = 0; m < MT; ++m)
                gk[m] = __builtin_amdgcn_mfma_f32_16x16x32_bf16(ah[m], bhi, gk[m], 0, 0, 0);
            #pragma unroll
            for (int m = 0; m < MT; ++m)
                gk[m] = __builtin_amdgcn_mfma_f32_16x16x32_bf16(ah[m], blo, gk[m], 0, 0, 0);
            #pragma unroll
            for (int m = 0; m < MT; ++m)
                gk[m] = __builtin_amdgcn_mfma_f32_16x16x32_bf16(al[m], bhi, gk[m], 0, 0, 0);
        }
        #pragma unroll
        for (int m = 0; m < MT; ++m) {
            #pragma unroll
            for (int j = 0; j < 4; ++j) {
                const int row = wm * 112 + m * 16 + lg * 4 + j;
                const int u = row >> 2, g = row & 3;
                gk[m][j] += (u < 100) ? bl[g * 100 + u] : 0.f;
            }
        }
    }
    __syncthreads();   // x9(0) visible; ready for the loop

    // ---------------- main 40-step recurrence (2 barriers/step) ----------------
    int cb = 0;
    for (int t = 0; t < TS; ++t) {
        char* Hhi_c = sm + HB_OFF + cb * 16384;
        char* Hlo_c = Hhi_c + 8192;
        char* Hhi_n = sm + HB_OFF + (cb ^ 1) * 16384;
        char* Hlo_n = Hhi_n + 8192;

        // C) z^T = gk + W_comb @ [h ; x9]   (A resident in VGPRs, B = H_cur)
        f32x4 acc[MT];
        #pragma unroll
        for (int m = 0; m < MT; ++m) acc[m] = gk[m];
        #pragma unroll
        for (int kc = 0; kc < KC; ++kc) {
            const int off = hswz(b, kc * 64 + lg * 16);
            bf16x8 bhi = *(const bf16x8*)(Hhi_c + off);
            bf16x8 blo = *(const bf16x8*)(Hlo_c + off);
            #pragma unroll
            for (int m = 0; m < MT; ++m)
                acc[m] = __builtin_amdgcn_mfma_f32_16x16x32_bf16(afr[m][kc], bhi, acc[m], 0, 0, 0);
            #pragma unroll
            for (int m = 0; m < MT; ++m)
                acc[m] = __builtin_amdgcn_mfma_f32_16x16x32_bf16(afr[m][kc], blo, acc[m], 0, 0, 0);
        }

        // E) gates in-register ; h(t+1) -> H_next ; act partials
        float pact = 0.f;
        #pragma unroll
        for (int m = 0; m < MT; ++m) {
            const int u = wm * 28 + m * 4 + lg;
            f32x4 z = acc[m];
            const float cc = sigf(z[1]) * c_st[m] + sigf(z[0]) * tanhf_(z[2]);
            const float hh = sigf(z[3]) * tanhf_(cc);
            c_st[m] = cc;
            pact += hh * wd_reg[m];
            if (u < 100) {
                const unsigned short hi = f2bf(hh);
                const int off = hswz(b, 2 * u);
                *(unsigned short*)(Hhi_n + off) = hi;
                *(unsigned short*)(Hlo_n + off) = f2bf(hh - bf2f(hi));
            }
        }
        pact += __shfl_xor(pact, 16);
        pact += __shfl_xor(pact, 32);
        if (l < 16) part[wm * 32 + wn * 16 + l] = pact;
        __syncthreads();   // part + h(t+1) visible

        // G) act ; output ; x9(t+1) -> H_next ; advance idm prefetch
        if (env_owner) {
            const float act = part[b] + part[32 + b] + part[64 + b] + part[96 + b] + bd0;
            out[eg_env * TS + t] = act;
            if (t < TS - 1) {
                ego_v += act * 0.1f;
                ego_x += ego_v * 0.1f + 0.005f * act;
                const float f_veh_v = cur0[1], m_veh_v = cur0[2];
                const float f_glob_x = cur1[0], m_glob_x = cur1[1];
                const float ef_dv_t = cur1[2], ef_dx_t = cur1[3];
                const float em_dv_t = cur2[0], em_dx_t = cur2[1];
                const float f_ex = cur2[2], m_ex = cur2[3];
                const float ef_dx = (f_glob_x - ego_x) * f_ex + (1.f - f_ex) * ef_dx_t;
                const float em_dx = (m_glob_x - ego_x) * m_ex + (1.f - m_ex) * em_dx_t;
                const float ef_dv = (ego_v - f_veh_v) * f_ex + (1.f - f_ex) * ef_dv_t;
                const float em_dv = (ego_v - m_veh_v) * m_ex + (1.f - m_ex) * em_dv_t;
                float x9[9];
                x9[0] = curs[0]; x9[1] = curs[1];
                x9[2] = (ego_v   - ms[0]) * is[0];
                x9[3] = (f_veh_v - ms[1]) * is[1];
                x9[4] = (m_veh_v - ms[2]) * is[2];
                x9[5] = (ef_dv   - ms[3]) * is[3];
                x9[6] = (ef_dx   - ms[4]) * is[4];
                x9[7] = (em_dv   - ms[5]) * is[5];
                x9[8] = (em_dx   - ms[6]) * is[6];
                #pragma unroll
                for (int r = 0; r < 9; ++r) {
                    const unsigned short hi = f2bf(x9[r]);
                    const int off = hswz(b, 200 + 2 * r);
                    *(unsigned short*)(Hhi_n + off) = hi;
                    *(unsigned short*)(Hlo_n + off) = f2bf(x9[r] - bf2f(hi));
                }
                if (t < TS - 2) {
                    const float* ip = idm_s + (eg_env * TS + t + 2) * 12;
                    cur0 = *(const f32x4*)ip; cur1 = *(const f32x4*)(ip + 4); cur2 = *(const f32x4*)(ip + 8);
                    curs = *(const f32x2*)(sdv_acts + (eg_env * TS + t + 2) * 2);
                }
            }
        }
        __syncthreads();   // H_next complete
        cb ^= 1;
    }
}

extern "C" void kernel_launch(void* const* d_in, const int* in_sizes, int n_in,
                              void* d_out, int out_size, void* d_ws, size_t ws_size,
                              hipStream_t stream) {
    const float* sampled_z = (const float*)d_in[0];
    const float* idm_s     = (const float*)d_in[1];
    const float* sdv_acts  = (const float*)d_in[2];
    const float* W1        = (const float*)d_in[3];
    const float* b1        = (const float*)d_in[4];
    const float* W2        = (const float*)d_in[5];
    const float* b2        = (const float*)d_in[6];
    const float* Wk        = (const float*)d_in[7];
    const float* Wr        = (const float*)d_in[8];
    const float* bl        = (const float*)d_in[9];
    const float* Wd        = (const float*)d_in[10];
    const float* bd        = (const float*)d_in[11];
    const float* sc_mean   = (const float*)d_in[12];
    const float* sc_var    = (const float*)d_in[13];
    float* out = (float*)d_out;

    unsigned short* Am = (unsigned short*)d_ws;       // [448][128] bf16: Wr + Wk-env
    unsigned short* Ah = Am + 448 * 128;              // Wk[0:100] hi
    unsigned short* Al = Ah + 448 * 128;              // Wk[0:100] lo

    hipLaunchKernelGGL(prep_kernel, dim3(224), dim3(256), 0, stream, Wr, Wk, Am, Ah, Al);
    hipLaunchKernelGGL(fwdsim_kernel, dim3(16384 / BT), dim3(NT), 0, stream,
                       sampled_z, idm_s, sdv_acts, W1, b1, W2, b2, bl, Wd, bd,
                       sc_mean, sc_var, Am, Ah, Al, out);
}